// Round 5
// baseline (988.080 us; speedup 1.0000x reference)
//
#include <hip/hip_runtime.h>
#include <math.h>

#define NTOK   262144
#define DIM    64
#define NCODE  1024
#define LOSSOFF (NTOK*DIM)          // 16777216
#define IDXOFF  (NTOK*DIM + 1)      // indices written as float32

// ws layout (floats): [0,1024) = B[c] = fl32 sum(c^2); [1024,2048) = per-block loss partials

__global__ __launch_bounds__(256) void vq_prep(const float* __restrict__ cb,
                                               float* __restrict__ ws) {
    int c = blockIdx.x * 256 + threadIdx.x;
    if (c < NCODE) {
        const float4* p = (const float4*)(cb + (size_t)c * DIM);
        float a0 = 0.f, a1 = 0.f, a2 = 0.f, a3 = 0.f;
#pragma unroll
        for (int i = 0; i < 16; i++) {
            float4 v = p[i];
            a0 = fmaf(v.x, v.x, a0); a1 = fmaf(v.y, v.y, a1);
            a2 = fmaf(v.z, v.z, a2); a3 = fmaf(v.w, v.w, a3);
        }
        // exact order irrelevant: B uncertainty ~1e-12 vs rounding boundary 7.6e-6
        ws[c] = (a0 + a1) + (a2 + a3);
    }
}

// waves_per_eu(2,2): R2-R4 showed the allocator AGPR-homes xv[64] at any
// >=4-wave target (VGPR_Count=64 is arch-VGPRs only; the ~171 extra VALU
// instrs/iter = v_accvgpr_read per xv use). Capping occupancy at 2 waves/EU
// gives a 256-reg budget -> zero pressure -> xv stays in true VGPRs and the
// loop is ~128 v_fmac + bookkeeping. VALU work/SIMD is occupancy-invariant.
__global__ __launch_bounds__(256)
__attribute__((amdgpu_waves_per_eu(2, 2)))
void vq_main(const float* __restrict__ x,
             const float* __restrict__ cb,
             float* __restrict__ out,
             float* __restrict__ ws) {
    const float* bn = ws;          // B[c]
    float* blk = ws + 1024;        // loss partials

    int t = blockIdx.x * 256 + threadIdx.x;

    float xv[DIM];
    {
        const float4* p = (const float4*)(x + (size_t)t * DIM);
#pragma unroll
        for (int i = 0; i < 16; i++) {
            float4 v = p[i];
            xv[4 * i] = v.x; xv[4 * i + 1] = v.y;
            xv[4 * i + 2] = v.z; xv[4 * i + 3] = v.w;
        }
    }

    // A = ||x||^2 : any fp32 order (uniform-shift invariance of the argmin)
    float a0 = 0.f, a1 = 0.f, a2 = 0.f, a3 = 0.f;
#pragma unroll
    for (int k = 0; k < DIM; k += 4) {
        a0 = fmaf(xv[k],     xv[k],     a0);
        a1 = fmaf(xv[k + 1], xv[k + 1], a1);
        a2 = fmaf(xv[k + 2], xv[k + 2], a2);
        a3 = fmaf(xv[k + 3], xv[k + 3], a3);
    }
    float A = (a0 + a1) + (a2 + a3);

    float best = 3.4e38f;
    int bidx = 0;
    // Replicate np/BLAS fp32 semantics: dot = sequential FMA chain k=0..63,
    // D = fl( fl(A + B[c]) - 2*dot )  (x2 exact, fma-contraction bit-identical)
    for (int c = 0; c < NCODE; c += 2) {
        const float4* c0 = (const float4*)(cb + (size_t)c * DIM);
        const float4* c1 = (const float4*)(cb + (size_t)(c + 1) * DIM);
        float p0 = 0.f, p1 = 0.f;
#pragma unroll
        for (int i = 0; i < 16; i++) {
            float4 u = c0[i], w = c1[i];
            p0 = fmaf(xv[4 * i + 0], u.x, p0); p1 = fmaf(xv[4 * i + 0], w.x, p1);
            p0 = fmaf(xv[4 * i + 1], u.y, p0); p1 = fmaf(xv[4 * i + 1], w.y, p1);
            p0 = fmaf(xv[4 * i + 2], u.z, p0); p1 = fmaf(xv[4 * i + 2], w.z, p1);
            p0 = fmaf(xv[4 * i + 3], u.w, p0); p1 = fmaf(xv[4 * i + 3], w.w, p1);
        }
        float s0 = A + bn[c];
        float s1 = A + bn[c + 1];
        float d0 = s0 - 2.0f * p0;
        float d1 = s1 - 2.0f * p1;
        // strict <, ascending c: np.argmin first-min semantics (d0 before d1)
        bool l0 = d0 < best;
        best = l0 ? d0 : best; bidx = l0 ? c : bidx;
        bool l1 = d1 < best;
        best = l1 ? d1 : best; bidx = l1 ? (c + 1) : bidx;
    }

    // epilogue: quantized = fl(x + fl(q - x)) (straight-through, ref-exact bits)
    float sqerr = 0.f;
    {
        const float4* qp = (const float4*)(cb + (size_t)bidx * DIM);
        float4* qo = (float4*)(out + (size_t)t * DIM);
#pragma unroll
        for (int i = 0; i < 16; i++) {
            float4 q = qp[i];
            float d0 = q.x - xv[4 * i + 0];
            float d1 = q.y - xv[4 * i + 1];
            float d2 = q.z - xv[4 * i + 2];
            float d3 = q.w - xv[4 * i + 3];
            float4 o;
            o.x = xv[4 * i + 0] + d0; o.y = xv[4 * i + 1] + d1;
            o.z = xv[4 * i + 2] + d2; o.w = xv[4 * i + 3] + d3;
            qo[i] = o;
            sqerr += d0 * d0 + d1 * d1 + d2 * d2 + d3 * d3;
        }
    }
    out[IDXOFF + t] = (float)bidx;

    // block loss partial
    for (int off = 32; off; off >>= 1) sqerr += __shfl_down(sqerr, off, 64);
    __shared__ float red[4];
    int lane = threadIdx.x & 63, wid = threadIdx.x >> 6;
    if (lane == 0) red[wid] = sqerr;
    __syncthreads();
    if (threadIdx.x == 0)
        blk[blockIdx.x] = (red[0] + red[1]) + (red[2] + red[3]);
}

__global__ __launch_bounds__(256) void vq_loss(float* __restrict__ out,
                                               const float* __restrict__ ws) {
    const float* blk = ws + 1024;
    __shared__ double sd[256];
    double s = 0.0;
    for (int i = threadIdx.x; i < 1024; i += 256) s += (double)blk[i];
    sd[threadIdx.x] = s;
    __syncthreads();
    for (int off = 128; off; off >>= 1) {
        if (threadIdx.x < off) sd[threadIdx.x] += sd[threadIdx.x + off];
        __syncthreads();
    }
    if (threadIdx.x == 0)
        out[LOSSOFF] = (float)(1.25 * sd[0] / ((double)NTOK * (double)DIM));
}

extern "C" void kernel_launch(void* const* d_in, const int* in_sizes, int n_in,
                              void* d_out, int out_size, void* d_ws, size_t ws_size,
                              hipStream_t stream) {
    (void)in_sizes; (void)n_in; (void)out_size; (void)ws_size;
    const float* x = (const float*)d_in[0];
    const float* cb = (const float*)d_in[1];
    float* out = (float*)d_out;
    float* ws = (float*)d_ws;

    hipLaunchKernelGGL(vq_prep, dim3(4), dim3(256), 0, stream, cb, ws);
    hipLaunchKernelGGL(vq_main, dim3(NTOK / 256), dim3(256), 0, stream, x, cb, out, ws);
    hipLaunchKernelGGL(vq_loss, dim3(1), dim3(256), 0, stream, out, ws);
}

// Round 6
// 435.272 us; speedup vs baseline: 2.2700x; 2.2700x over previous
//
#include <hip/hip_runtime.h>
#include <math.h>

#define NTOK   262144
#define DIM    64
#define NCODE  1024
#define LOSSOFF (NTOK*DIM)          // 16777216
#define IDXOFF  (NTOK*DIM + 1)

#define MARGIN 8e-5f
#define RCAP   65536

// ws float-offsets (new path)
#define OFF_BC     0               // 1024 f
#define OFF_CBHI   1024            // ushort[65536] = 32768 f
#define OFF_CBMID  33792           // 32768 f
#define OFF_RCNT   66560           // 1 (int)
#define OFF_RLIST  66561           // 65536 (int)
#define OFF_BLK    132097          // 16384 f
#define WS_FLOATS  148481

typedef __attribute__((ext_vector_type(8))) short short8;
typedef __attribute__((ext_vector_type(4))) float f32x4;

__device__ __forceinline__ ushort bf16rn(float f) {
    unsigned u = __float_as_uint(f);
    return (ushort)((u + 0x7fffu + ((u >> 16) & 1u)) >> 16);
}
__device__ __forceinline__ float bf16tof(ushort h) {
    return __uint_as_float(((unsigned)h) << 16);
}

// ---------------- new path ----------------

__global__ __launch_bounds__(256) void vq_prep_cb(const float* __restrict__ cb,
                                                  float* __restrict__ ws) {
    int c = blockIdx.x * 256 + threadIdx.x;
    if (c == 0) ((int*)ws)[OFF_RCNT] = 0;
    if (c >= NCODE) return;
    ushort* cbh = (ushort*)(ws + OFF_CBHI);
    ushort* cbm = (ushort*)(ws + OFF_CBMID);
    const float4* p = (const float4*)(cb + (size_t)c * DIM);
    float a0 = 0.f, a1 = 0.f, a2 = 0.f, a3 = 0.f;
#pragma unroll
    for (int i = 0; i < 16; i++) {
        float4 v = p[i];
        a0 = fmaf(v.x, v.x, a0); a1 = fmaf(v.y, v.y, a1);
        a2 = fmaf(v.z, v.z, a2); a3 = fmaf(v.w, v.w, a3);
        ushort4 h, m;
        h.x = bf16rn(v.x); m.x = bf16rn(v.x - bf16tof(h.x));
        h.y = bf16rn(v.y); m.y = bf16rn(v.y - bf16tof(h.y));
        h.z = bf16rn(v.z); m.z = bf16rn(v.z - bf16tof(h.z));
        h.w = bf16rn(v.w); m.w = bf16rn(v.w - bf16tof(h.w));
        ((ushort4*)(cbh + (size_t)c * 64))[i] = h;
        ((ushort4*)(cbm + (size_t)c * 64))[i] = m;
    }
    ws[OFF_BC + c] = (a0 + a1) + (a2 + a3);   // same chain as proven R2 prep
}

// A = codebook (16 codes x 32k), B = x (32k x 16 tokens), C[code][token].
// Frag maps (gfx950 16x16x32): A row=lane&15,k=(lane>>4)*8+j; B col=lane&15,
// same k; C col=lane&15,row=(lane>>4)*4+r. Wave: 2 token-tiles (32 tokens);
// WG = 4 waves = 128 tokens; codebook-split tiles staged in LDS (xor-swizzled).
__global__ __launch_bounds__(256) void vq_mfma(const float* __restrict__ x,
                                               float* __restrict__ out,
                                               float* __restrict__ ws) {
    __shared__ uint4 smem[256];   // 4KB: [chunk(2)][code(16)][granule(8)] 16B
    const float* Bc = ws + OFF_BC;
    const ushort* cbh = (const ushort*)(ws + OFF_CBHI);
    const ushort* cbm = (const ushort*)(ws + OFF_CBMID);

    int tid = threadIdx.x, lane = tid & 63, wv = tid >> 6;
    int col = lane & 15, q = lane >> 4;
    int tokb = blockIdx.x * 128 + wv * 32;

    short8 Xhi[2][2], Xmid[2][2];
    float S[2];
#pragma unroll
    for (int tt = 0; tt < 2; ++tt) {
        int token = tokb + tt * 16 + col;
        const float* xr = x + (size_t)token * 64;
        float ss = 0.f;
#pragma unroll
        for (int s = 0; s < 2; ++s) {
            float4 v0 = *(const float4*)(xr + s * 32 + q * 8);
            float4 v1 = *(const float4*)(xr + s * 32 + q * 8 + 4);
            float vv[8] = {v0.x, v0.y, v0.z, v0.w, v1.x, v1.y, v1.z, v1.w};
            short8 hv, mv;
#pragma unroll
            for (int j = 0; j < 8; ++j) {
                ushort h = bf16rn(vv[j]);
                float r = vv[j] - bf16tof(h);   // exact (Sterbenz)
                hv[j] = (short)h; mv[j] = (short)bf16rn(r);
                ss = fmaf(vv[j], vv[j], ss);
            }
            Xhi[tt][s] = hv; Xmid[tt][s] = mv;
        }
        ss += __shfl_xor(ss, 16, 64);
        ss += __shfl_xor(ss, 32, 64);
        S[tt] = ss;
    }

    float best[2] = {3.4e38f, 3.4e38f}, sec[2] = {3.4e38f, 3.4e38f};
    int bidx[2] = {0, 0};

    for (int tile = 0; tile < 64; ++tile) {
        int c0 = tile * 16;
        __syncthreads();
        {   // stage 4KB of cb splits; swizzle granule ^= code&7 (bank-spread)
            int chunk = tid >> 7, e = tid & 127, code = e >> 3, g = e & 7;
            const ushort* src = (chunk ? cbm : cbh) + (size_t)(c0 + code) * 64 + g * 8;
            smem[chunk * 128 + code * 8 + (g ^ (code & 7))] = *(const uint4*)src;
        }
        __syncthreads();
        short8 Ah[2], Am[2];
#pragma unroll
        for (int st = 0; st < 2; ++st) {
            int gg = st * 4 + q;
            Ah[st] = *(const short8*)&smem[col * 8 + (gg ^ (col & 7))];
            Am[st] = *(const short8*)&smem[128 + col * 8 + (gg ^ (col & 7))];
        }
        float bcv[4];
#pragma unroll
        for (int r = 0; r < 4; ++r) bcv[r] = Bc[c0 + q * 4 + r];
#pragma unroll
        for (int tt = 0; tt < 2; ++tt) {
            f32x4 acc = {0.f, 0.f, 0.f, 0.f};
            acc = __builtin_amdgcn_mfma_f32_16x16x32_bf16(Ah[0], Xhi[tt][0], acc, 0, 0, 0);
            acc = __builtin_amdgcn_mfma_f32_16x16x32_bf16(Ah[1], Xhi[tt][1], acc, 0, 0, 0);
            acc = __builtin_amdgcn_mfma_f32_16x16x32_bf16(Ah[0], Xmid[tt][0], acc, 0, 0, 0);
            acc = __builtin_amdgcn_mfma_f32_16x16x32_bf16(Ah[1], Xmid[tt][1], acc, 0, 0, 0);
            acc = __builtin_amdgcn_mfma_f32_16x16x32_bf16(Am[0], Xhi[tt][0], acc, 0, 0, 0);
            acc = __builtin_amdgcn_mfma_f32_16x16x32_bf16(Am[1], Xhi[tt][1], acc, 0, 0, 0);
#pragma unroll
            for (int r = 0; r < 4; ++r) {
                float d = fmaf(-2.f, acc[r], S[tt] + bcv[r]);
                int ci = c0 + q * 4 + r;
                float mx = fmaxf(d, best[tt]);
                bool lt = d < best[tt];
                sec[tt] = fminf(sec[tt], mx);
                best[tt] = lt ? d : best[tt];
                bidx[tt] = lt ? ci : bidx[tt];
            }
        }
    }

#pragma unroll
    for (int tt = 0; tt < 2; ++tt) {
        float b = best[tt], s2 = sec[tt]; int bi = bidx[tt];
#pragma unroll
        for (int off = 16; off <= 32; off <<= 1) {
            float ob = __shfl_xor(b, off, 64);
            float os = __shfl_xor(s2, off, 64);
            int   oi = __shfl_xor(bi, off, 64);
            s2 = fminf(fminf(s2, os), fmaxf(b, ob));
            bool lt = (ob < b) || (ob == b && oi < bi);
            b = lt ? ob : b; bi = lt ? oi : bi;
        }
        if (lane < 16) {
            int token = tokb + tt * 16 + lane;
            out[IDXOFF + token] = (float)bi;
            if (s2 - b < MARGIN) {
                int pos = atomicAdd((int*)ws + OFF_RCNT, 1);
                if (pos < RCAP) ((int*)ws)[OFF_RLIST + pos] = token;
            }
        }
    }
}

// exact fp32 re-scan (R2-proven semantics) for flagged tokens
__global__ __launch_bounds__(256) void vq_refine(const float* __restrict__ x,
                                                 const float* __restrict__ cb,
                                                 float* __restrict__ out,
                                                 float* __restrict__ ws) {
    int cnt = min(((int*)ws)[OFF_RCNT], RCAP);
    __shared__ float xs[64];
    __shared__ float fval[256];
    __shared__ int   fidx[256];
    for (int i = blockIdx.x; i < cnt; i += gridDim.x) {
        int t = ((int*)ws)[OFF_RLIST + i];
        __syncthreads();
        if (threadIdx.x < 64) xs[threadIdx.x] = x[(size_t)t * 64 + threadIdx.x];
        __syncthreads();
        float a0 = 0.f, a1 = 0.f, a2 = 0.f, a3 = 0.f;
#pragma unroll
        for (int kc = 0; kc < 16; ++kc) {
            float4 xk = *(const float4*)(xs + kc * 4);
            a0 = fmaf(xk.x, xk.x, a0); a1 = fmaf(xk.y, xk.y, a1);
            a2 = fmaf(xk.z, xk.z, a2); a3 = fmaf(xk.w, xk.w, a3);
        }
        float A = (a0 + a1) + (a2 + a3);
        float p[4] = {0.f, 0.f, 0.f, 0.f};
        int cbase = threadIdx.x * 4;
#pragma unroll 4
        for (int kc = 0; kc < 16; ++kc) {
            float4 xk = *(const float4*)(xs + kc * 4);
#pragma unroll
            for (int j = 0; j < 4; ++j) {
                float4 cv = *(const float4*)(cb + (size_t)(cbase + j) * 64 + kc * 4);
                p[j] = fmaf(xk.x, cv.x, p[j]);
                p[j] = fmaf(xk.y, cv.y, p[j]);
                p[j] = fmaf(xk.z, cv.z, p[j]);
                p[j] = fmaf(xk.w, cv.w, p[j]);
            }
        }
        float bb = 3.4e38f; int bi = 0;
#pragma unroll
        for (int j = 0; j < 4; ++j) {
            float s = A + ws[OFF_BC + cbase + j];
            float d = fmaf(-2.0f, p[j], s);   // == fl(s - 2p): 2p exact
            if (d < bb) { bb = d; bi = cbase + j; }
        }
        fval[threadIdx.x] = bb; fidx[threadIdx.x] = bi;
        __syncthreads();
        for (int off = 128; off; off >>= 1) {
            if (threadIdx.x < off) {
                float ov = fval[threadIdx.x + off]; int oi = fidx[threadIdx.x + off];
                if (ov < fval[threadIdx.x] ||
                    (ov == fval[threadIdx.x] && oi < fidx[threadIdx.x])) {
                    fval[threadIdx.x] = ov; fidx[threadIdx.x] = oi;
                }
            }
            __syncthreads();
        }
        if (threadIdx.x == 0) out[IDXOFF + t] = (float)fidx[0];
    }
}

__global__ __launch_bounds__(256) void vq_out(const float* __restrict__ x,
                                              const float* __restrict__ cb,
                                              float* __restrict__ out,
                                              float* __restrict__ ws) {
    int g = blockIdx.x * 256 + threadIdx.x;
    int token = g >> 4, quad = g & 15;
    int ci = (int)out[IDXOFF + token];
    float4 xv = *(const float4*)(x + (size_t)token * 64 + quad * 4);
    float4 qv = *(const float4*)(cb + (size_t)ci * 64 + quad * 4);
    float d0 = qv.x - xv.x, d1 = qv.y - xv.y, d2 = qv.z - xv.z, d3 = qv.w - xv.w;
    float4 o; o.x = xv.x + d0; o.y = xv.y + d1; o.z = xv.z + d2; o.w = xv.w + d3;
    *(float4*)(out + (size_t)token * 64 + quad * 4) = o;
    float se = d0 * d0 + d1 * d1 + d2 * d2 + d3 * d3;
    for (int off = 32; off; off >>= 1) se += __shfl_down(se, off, 64);
    __shared__ float red[4];
    if ((threadIdx.x & 63) == 0) red[threadIdx.x >> 6] = se;
    __syncthreads();
    if (threadIdx.x == 0) ws[OFF_BLK + blockIdx.x] = (red[0] + red[1]) + (red[2] + red[3]);
}

__global__ __launch_bounds__(256) void vq_loss2(float* __restrict__ out,
                                                const float* __restrict__ ws) {
    const float* blk = ws + OFF_BLK;
    __shared__ double sd[256];
    double s = 0.0;
    for (int i = threadIdx.x; i < 16384; i += 256) s += (double)blk[i];
    sd[threadIdx.x] = s;
    __syncthreads();
    for (int off = 128; off; off >>= 1) {
        if (threadIdx.x < off) sd[threadIdx.x] += sd[threadIdx.x + off];
        __syncthreads();
    }
    if (threadIdx.x == 0)
        out[LOSSOFF] = (float)(1.25 * sd[0] / ((double)NTOK * (double)DIM));
}

// ---------------- fallback path (R2, proven @750us) ----------------

__global__ __launch_bounds__(256) void vq_prep_fb(const float* __restrict__ cb,
                                                  float* __restrict__ ws) {
    int c = blockIdx.x * 256 + threadIdx.x;
    if (c < NCODE) {
        const float4* p = (const float4*)(cb + (size_t)c * DIM);
        float a0 = 0.f, a1 = 0.f, a2 = 0.f, a3 = 0.f;
#pragma unroll
        for (int i = 0; i < 16; i++) {
            float4 v = p[i];
            a0 = fmaf(v.x, v.x, a0); a1 = fmaf(v.y, v.y, a1);
            a2 = fmaf(v.z, v.z, a2); a3 = fmaf(v.w, v.w, a3);
        }
        ws[c] = (a0 + a1) + (a2 + a3);
    }
}

__global__ __launch_bounds__(256) void vq_main_fb(const float* __restrict__ x,
                                                  const float* __restrict__ cb,
                                                  float* __restrict__ out,
                                                  float* __restrict__ ws) {
    const float* bn = ws;
    float* blk = ws + 1024;
    int t = blockIdx.x * 256 + threadIdx.x;
    float xv[DIM];
    {
        const float4* p = (const float4*)(x + (size_t)t * DIM);
#pragma unroll
        for (int i = 0; i < 16; i++) {
            float4 v = p[i];
            xv[4 * i] = v.x; xv[4 * i + 1] = v.y;
            xv[4 * i + 2] = v.z; xv[4 * i + 3] = v.w;
        }
    }
    float a0 = 0.f, a1 = 0.f, a2 = 0.f, a3 = 0.f;
#pragma unroll
    for (int k = 0; k < DIM; k += 4) {
        a0 = fmaf(xv[k], xv[k], a0); a1 = fmaf(xv[k + 1], xv[k + 1], a1);
        a2 = fmaf(xv[k + 2], xv[k + 2], a2); a3 = fmaf(xv[k + 3], xv[k + 3], a3);
    }
    float A = (a0 + a1) + (a2 + a3);
    float best = 3.4e38f; int bidx = 0;
    for (int c = 0; c < NCODE; c += 2) {
        const float4* c0 = (const float4*)(cb + (size_t)c * DIM);
        const float4* c1 = (const float4*)(cb + (size_t)(c + 1) * DIM);
        float p0 = 0.f, p1 = 0.f;
#pragma unroll
        for (int i = 0; i < 16; i++) {
            float4 u = c0[i], w = c1[i];
            p0 = fmaf(xv[4 * i + 0], u.x, p0); p1 = fmaf(xv[4 * i + 0], w.x, p1);
            p0 = fmaf(xv[4 * i + 1], u.y, p0); p1 = fmaf(xv[4 * i + 1], w.y, p1);
            p0 = fmaf(xv[4 * i + 2], u.z, p0); p1 = fmaf(xv[4 * i + 2], w.z, p1);
            p0 = fmaf(xv[4 * i + 3], u.w, p0); p1 = fmaf(xv[4 * i + 3], w.w, p1);
        }
        float s0 = A + bn[c], s1 = A + bn[c + 1];
        float d0 = s0 - 2.0f * p0, d1 = s1 - 2.0f * p1;
        bool l0 = d0 < best; best = l0 ? d0 : best; bidx = l0 ? c : bidx;
        bool l1 = d1 < best; best = l1 ? d1 : best; bidx = l1 ? (c + 1) : bidx;
    }
    float sqerr = 0.f;
    {
        const float4* qp = (const float4*)(cb + (size_t)bidx * DIM);
        float4* qo = (float4*)(out + (size_t)t * DIM);
#pragma unroll
        for (int i = 0; i < 16; i++) {
            float4 qv = qp[i];
            float d0 = qv.x - xv[4 * i], d1 = qv.y - xv[4 * i + 1];
            float d2 = qv.z - xv[4 * i + 2], d3 = qv.w - xv[4 * i + 3];
            float4 o;
            o.x = xv[4 * i] + d0; o.y = xv[4 * i + 1] + d1;
            o.z = xv[4 * i + 2] + d2; o.w = xv[4 * i + 3] + d3;
            qo[i] = o;
            sqerr += d0 * d0 + d1 * d1 + d2 * d2 + d3 * d3;
        }
    }
    out[IDXOFF + t] = (float)bidx;
    for (int off = 32; off; off >>= 1) sqerr += __shfl_down(sqerr, off, 64);
    __shared__ float red[4];
    if ((threadIdx.x & 63) == 0) red[threadIdx.x >> 6] = sqerr;
    __syncthreads();
    if (threadIdx.x == 0) blk[blockIdx.x] = (red[0] + red[1]) + (red[2] + red[3]);
}

__global__ __launch_bounds__(256) void vq_loss_fb(float* __restrict__ out,
                                                  const float* __restrict__ ws) {
    const float* blk = ws + 1024;
    __shared__ double sd[256];
    double s = 0.0;
    for (int i = threadIdx.x; i < 1024; i += 256) s += (double)blk[i];
    sd[threadIdx.x] = s;
    __syncthreads();
    for (int off = 128; off; off >>= 1) {
        if (threadIdx.x < off) sd[threadIdx.x] += sd[threadIdx.x + off];
        __syncthreads();
    }
    if (threadIdx.x == 0)
        out[LOSSOFF] = (float)(1.25 * sd[0] / ((double)NTOK * (double)DIM));
}

extern "C" void kernel_launch(void* const* d_in, const int* in_sizes, int n_in,
                              void* d_out, int out_size, void* d_ws, size_t ws_size,
                              hipStream_t stream) {
    (void)in_sizes; (void)n_in; (void)out_size;
    const float* x = (const float*)d_in[0];
    const float* cb = (const float*)d_in[1];
    float* out = (float*)d_out;
    float* ws = (float*)d_ws;

    if (ws_size >= (size_t)WS_FLOATS * 4) {
        hipLaunchKernelGGL(vq_prep_cb, dim3(4), dim3(256), 0, stream, cb, ws);
        hipLaunchKernelGGL(vq_mfma, dim3(2048), dim3(256), 0, stream, x, out, ws);
        hipLaunchKernelGGL(vq_refine, dim3(2048), dim3(256), 0, stream, x, cb, out, ws);
        hipLaunchKernelGGL(vq_out, dim3(16384), dim3(256), 0, stream, x, cb, out, ws);
        hipLaunchKernelGGL(vq_loss2, dim3(1), dim3(256), 0, stream, out, ws);
    } else {
        hipLaunchKernelGGL(vq_prep_fb, dim3(4), dim3(256), 0, stream, cb, ws);
        hipLaunchKernelGGL(vq_main_fb, dim3(NTOK / 256), dim3(256), 0, stream, x, cb, out, ws);
        hipLaunchKernelGGL(vq_loss_fb, dim3(1), dim3(256), 0, stream, out, ws);
    }
}

// Round 7
// 249.232 us; speedup vs baseline: 3.9645x; 1.7465x over previous
//
#include <hip/hip_runtime.h>
#include <math.h>

#define NTOK   262144
#define DIM    64
#define NCODE  1024
#define LOSSOFF (NTOK*DIM)          // 16777216
#define IDXOFF  (NTOK*DIM + 1)

#define MARGIN 8e-5f
#define RCAP   65536

// ws float-offsets
#define OFF_BC     0               // 1024 f
#define OFF_CBHI   1024            // ushort[65536] = 32768 f
#define OFF_CBMID  33792           // 32768 f
#define OFF_RCNT   66560           // 1 (int)
#define OFF_RLIST  66561           // 65536 (int)
#define OFF_BLK    132097          // 16384 f
#define WS_FLOATS  148481

typedef __attribute__((ext_vector_type(8))) short short8;
typedef __attribute__((ext_vector_type(4))) float f32x4;

__device__ __forceinline__ ushort bf16rn(float f) {
    unsigned u = __float_as_uint(f);
    return (ushort)((u + 0x7fffu + ((u >> 16) & 1u)) >> 16);
}
__device__ __forceinline__ float bf16tof(ushort h) {
    return __uint_as_float(((unsigned)h) << 16);
}

__global__ __launch_bounds__(256) void vq_prep_cb(const float* __restrict__ cb,
                                                  float* __restrict__ ws) {
    int c = blockIdx.x * 256 + threadIdx.x;
    if (c == 0) ((int*)ws)[OFF_RCNT] = 0;
    if (c >= NCODE) return;
    ushort* cbh = (ushort*)(ws + OFF_CBHI);
    ushort* cbm = (ushort*)(ws + OFF_CBMID);
    const float4* p = (const float4*)(cb + (size_t)c * DIM);
    float a0 = 0.f, a1 = 0.f, a2 = 0.f, a3 = 0.f;
#pragma unroll
    for (int i = 0; i < 16; i++) {
        float4 v = p[i];
        a0 = fmaf(v.x, v.x, a0); a1 = fmaf(v.y, v.y, a1);
        a2 = fmaf(v.z, v.z, a2); a3 = fmaf(v.w, v.w, a3);
        ushort4 h, m;
        h.x = bf16rn(v.x); m.x = bf16rn(v.x - bf16tof(h.x));
        h.y = bf16rn(v.y); m.y = bf16rn(v.y - bf16tof(h.y));
        h.z = bf16rn(v.z); m.z = bf16rn(v.z - bf16tof(h.z));
        h.w = bf16rn(v.w); m.w = bf16rn(v.w - bf16tof(h.w));
        ((ushort4*)(cbh + (size_t)c * 64))[i] = h;
        ((ushort4*)(cbm + (size_t)c * 64))[i] = m;
    }
    ws[OFF_BC + c] = (a0 + a1) + (a2 + a3);   // exact R2 prep chain
}

// MFMA distance pass; double-buffered LDS staging of bf16 hi/mid code tiles.
__global__ __launch_bounds__(256) void vq_mfma(const float* __restrict__ x,
                                               float* __restrict__ out,
                                               float* __restrict__ ws) {
    __shared__ uint4 smem[2][256];   // 8KB: [buf][chunk(2)][code(16)][granule(8)]
    const float* Bc = ws + OFF_BC;
    const ushort* cbh = (const ushort*)(ws + OFF_CBHI);
    const ushort* cbm = (const ushort*)(ws + OFF_CBMID);

    int tid = threadIdx.x, lane = tid & 63, wv = tid >> 6;
    int col = lane & 15, q = lane >> 4;
    int tokb = blockIdx.x * 128 + wv * 32;

    short8 Xhi[2][2], Xmid[2][2];
    float S[2];
#pragma unroll
    for (int tt = 0; tt < 2; ++tt) {
        int token = tokb + tt * 16 + col;
        const float* xr = x + (size_t)token * 64;
        float ss = 0.f;
#pragma unroll
        for (int s = 0; s < 2; ++s) {
            float4 v0 = *(const float4*)(xr + s * 32 + q * 8);
            float4 v1 = *(const float4*)(xr + s * 32 + q * 8 + 4);
            float vv[8] = {v0.x, v0.y, v0.z, v0.w, v1.x, v1.y, v1.z, v1.w};
            short8 hv, mv;
#pragma unroll
            for (int j = 0; j < 8; ++j) {
                ushort h = bf16rn(vv[j]);
                float r = vv[j] - bf16tof(h);
                hv[j] = (short)h; mv[j] = (short)bf16rn(r);
                ss = fmaf(vv[j], vv[j], ss);
            }
            Xhi[tt][s] = hv; Xmid[tt][s] = mv;
        }
        ss += __shfl_xor(ss, 16, 64);
        ss += __shfl_xor(ss, 32, 64);
        S[tt] = ss;
    }

    float best[2] = {3.4e38f, 3.4e38f}, sec[2] = {3.4e38f, 3.4e38f};
    int bidx[2] = {0, 0};

    int chunk = tid >> 7, e = tid & 127, scode = e >> 3, g = e & 7;
    const ushort* sb0 = (chunk ? cbm : cbh);
    // prologue load (tile 0)
    uint4 r = *(const uint4*)(sb0 + (size_t)scode * 64 + g * 8);

    for (int tile = 0; tile < 64; ++tile) {
        int buf = tile & 1;
        smem[buf][chunk * 128 + scode * 8 + (g ^ (scode & 7))] = r;
        __syncthreads();
        if (tile < 63)   // prefetch next tile; latency hides under compute
            r = *(const uint4*)(sb0 + (size_t)((tile + 1) * 16 + scode) * 64 + g * 8);
        int c0 = tile * 16;
        short8 Ah[2], Am[2];
#pragma unroll
        for (int st = 0; st < 2; ++st) {
            int gg = st * 4 + q;
            Ah[st] = *(const short8*)&smem[buf][col * 8 + (gg ^ (col & 7))];
            Am[st] = *(const short8*)&smem[buf][128 + col * 8 + (gg ^ (col & 7))];
        }
        float bcv[4];
#pragma unroll
        for (int rr = 0; rr < 4; ++rr) bcv[rr] = Bc[c0 + q * 4 + rr];
#pragma unroll
        for (int tt = 0; tt < 2; ++tt) {
            f32x4 acc = {0.f, 0.f, 0.f, 0.f};
            acc = __builtin_amdgcn_mfma_f32_16x16x32_bf16(Ah[0], Xhi[tt][0], acc, 0, 0, 0);
            acc = __builtin_amdgcn_mfma_f32_16x16x32_bf16(Ah[1], Xhi[tt][1], acc, 0, 0, 0);
            acc = __builtin_amdgcn_mfma_f32_16x16x32_bf16(Ah[0], Xmid[tt][0], acc, 0, 0, 0);
            acc = __builtin_amdgcn_mfma_f32_16x16x32_bf16(Ah[1], Xmid[tt][1], acc, 0, 0, 0);
            acc = __builtin_amdgcn_mfma_f32_16x16x32_bf16(Am[0], Xhi[tt][0], acc, 0, 0, 0);
            acc = __builtin_amdgcn_mfma_f32_16x16x32_bf16(Am[1], Xhi[tt][1], acc, 0, 0, 0);
#pragma unroll
            for (int rr = 0; rr < 4; ++rr) {
                float d = fmaf(-2.f, acc[rr], S[tt] + bcv[rr]);
                int ci = c0 + q * 4 + rr;
                float mx = fmaxf(d, best[tt]);
                bool lt = d < best[tt];
                sec[tt] = fminf(sec[tt], mx);
                best[tt] = lt ? d : best[tt];
                bidx[tt] = lt ? ci : bidx[tt];
            }
        }
        __syncthreads();
    }

#pragma unroll
    for (int tt = 0; tt < 2; ++tt) {
        float b = best[tt], s2 = sec[tt]; int bi = bidx[tt];
#pragma unroll
        for (int off = 16; off <= 32; off <<= 1) {
            float ob = __shfl_xor(b, off, 64);
            float os = __shfl_xor(s2, off, 64);
            int   oi = __shfl_xor(bi, off, 64);
            s2 = fminf(fminf(s2, os), fmaxf(b, ob));
            bool lt = (ob < b) || (ob == b && oi < bi);
            b = lt ? ob : b; bi = lt ? oi : bi;
        }
        if (lane < 16) {
            int token = tokb + tt * 16 + lane;
            out[IDXOFF + token] = (float)bi;
            if (s2 - b < MARGIN) {
                int pos = atomicAdd((int*)ws + OFF_RCNT, 1);
                if (pos < RCAP) ((int*)ws)[OFF_RLIST + pos] = token;
            }
        }
    }
}

// refine v3: 8 tokens/group; codebook staged coalesced to LDS in 128-code
// tiles (swizzled quads -> conflict-free b128 reads); exact R2 fp32 chains;
// packed (f32bits<<32)|idx u64-min = first-min tiebreak (d>0 always).
__global__ __launch_bounds__(256) void vq_refine(const float* __restrict__ x,
                                                 const float* __restrict__ cb,
                                                 float* __restrict__ out,
                                                 float* __restrict__ ws) {
    __shared__ float ctile[128][64];               // 32KB
    __shared__ float xs[8][64];                    // 2KB
    __shared__ float As[8];
    __shared__ int   tokid[8];
    __shared__ unsigned long long rkeys[8][128];   // 8KB

    int cnt = min(((int*)ws)[OFF_RCNT], RCAP);
    if (cnt <= 0) return;
    int ngroups = (cnt + 7) >> 3;
    int tid = threadIdx.x;
    int code = tid & 127, th = tid >> 7;           // th: token-half (0..3 / 4..7)

    for (int grp = blockIdx.x; grp < ngroups; grp += gridDim.x) {
        if (tid < 8) {
            int i = grp * 8 + tid;
            tokid[tid] = ((int*)ws)[OFF_RLIST + min(i, cnt - 1)];
        }
        __syncthreads();
        // stage x rows (coalesced 64B per token-chunk)
#pragma unroll
        for (int it = 0; it < 2; ++it) {
            int idx = it * 256 + tid;
            xs[idx >> 6][idx & 63] = x[(size_t)tokid[idx >> 6] * 64 + (idx & 63)];
        }
        __syncthreads();
        if (tid < 8) {    // exact R2 A-chain per token
            float a0 = 0.f, a1 = 0.f, a2 = 0.f, a3 = 0.f;
#pragma unroll
            for (int kc = 0; kc < 16; ++kc) {
                float4 xk = *(const float4*)(xs[tid] + kc * 4);
                a0 = fmaf(xk.x, xk.x, a0); a1 = fmaf(xk.y, xk.y, a1);
                a2 = fmaf(xk.z, xk.z, a2); a3 = fmaf(xk.w, xk.w, a3);
            }
            As[tid] = (a0 + a1) + (a2 + a3);
        }

        unsigned long long bk[4] = {~0ull, ~0ull, ~0ull, ~0ull};
        int tb = th * 4;

        for (int pass = 0; pass < 8; ++pass) {
            int cbase = pass * 128;
            __syncthreads();   // also covers As readiness on pass 0
            // stage 32KB tile, coalesced; quad-swizzled dest
#pragma unroll
            for (int it = 0; it < 8; ++it) {
                int gi = it * 256 + tid;
                int cc = gi >> 4, qq = gi & 15;
                float4 v = *(const float4*)(cb + (size_t)(cbase + cc) * 64 + qq * 4);
                *(float4*)&ctile[cc][(qq ^ (cc & 15)) * 4] = v;
            }
            __syncthreads();

            float p0 = 0.f, p1 = 0.f, p2 = 0.f, p3 = 0.f;
#pragma unroll
            for (int qq = 0; qq < 16; ++qq) {
                float4 cv = *(const float4*)&ctile[code][(qq ^ (code & 15)) * 4];
                float4 x0 = *(const float4*)(xs[tb + 0] + qq * 4);
                float4 x1 = *(const float4*)(xs[tb + 1] + qq * 4);
                float4 x2 = *(const float4*)(xs[tb + 2] + qq * 4);
                float4 x3 = *(const float4*)(xs[tb + 3] + qq * 4);
                p0 = fmaf(x0.x, cv.x, p0); p0 = fmaf(x0.y, cv.y, p0);
                p0 = fmaf(x0.z, cv.z, p0); p0 = fmaf(x0.w, cv.w, p0);
                p1 = fmaf(x1.x, cv.x, p1); p1 = fmaf(x1.y, cv.y, p1);
                p1 = fmaf(x1.z, cv.z, p1); p1 = fmaf(x1.w, cv.w, p1);
                p2 = fmaf(x2.x, cv.x, p2); p2 = fmaf(x2.y, cv.y, p2);
                p2 = fmaf(x2.z, cv.z, p2); p2 = fmaf(x2.w, cv.w, p2);
                p3 = fmaf(x3.x, cv.x, p3); p3 = fmaf(x3.y, cv.y, p3);
                p3 = fmaf(x3.z, cv.z, p3); p3 = fmaf(x3.w, cv.w, p3);
            }
            float bn = ws[OFF_BC + cbase + code];
            int gcode = cbase + code;
            float pv[4] = {p0, p1, p2, p3};
#pragma unroll
            for (int j = 0; j < 4; ++j) {
                float s = As[tb + j] + bn;
                float d = fmaf(-2.0f, pv[j], s);   // == fl(s - 2p)
                unsigned long long key =
                    (((unsigned long long)__float_as_uint(d)) << 32) | (unsigned)gcode;
                bk[j] = min(bk[j], key);
            }
        }
        __syncthreads();
#pragma unroll
        for (int j = 0; j < 4; ++j) rkeys[tb + j][code] = bk[j];
        __syncthreads();

        int wv = tid >> 6, lane = tid & 63;
#pragma unroll
        for (int u = 0; u < 2; ++u) {
            int tt = wv * 2 + u;
            unsigned long long k = min(rkeys[tt][lane], rkeys[tt][lane + 64]);
#pragma unroll
            for (int off = 32; off; off >>= 1)
                k = min(k, (unsigned long long)__shfl_xor((long long)k, off, 64));
            if (lane == 0 && grp * 8 + tt < cnt)
                out[IDXOFF + tokid[tt]] = (float)(int)(unsigned)(k & 0xffffffffull);
        }
        __syncthreads();
    }
}

__global__ __launch_bounds__(256) void vq_out(const float* __restrict__ x,
                                              const float* __restrict__ cb,
                                              float* __restrict__ out,
                                              float* __restrict__ ws) {
    int gidx = blockIdx.x * 256 + threadIdx.x;
    int token = gidx >> 4, quad = gidx & 15;
    int ci = (int)out[IDXOFF + token];
    float4 xv = *(const float4*)(x + (size_t)token * 64 + quad * 4);
    float4 qv = *(const float4*)(cb + (size_t)ci * 64 + quad * 4);
    float d0 = qv.x - xv.x, d1 = qv.y - xv.y, d2 = qv.z - xv.z, d3 = qv.w - xv.w;
    float4 o; o.x = xv.x + d0; o.y = xv.y + d1; o.z = xv.z + d2; o.w = xv.w + d3;
    *(float4*)(out + (size_t)token * 64 + quad * 4) = o;
    float se = d0 * d0 + d1 * d1 + d2 * d2 + d3 * d3;
    for (int off = 32; off; off >>= 1) se += __shfl_down(se, off, 64);
    __shared__ float red[4];
    if ((threadIdx.x & 63) == 0) red[threadIdx.x >> 6] = se;
    __syncthreads();
    if (threadIdx.x == 0) ws[OFF_BLK + blockIdx.x] = (red[0] + red[1]) + (red[2] + red[3]);
}

__global__ __launch_bounds__(256) void vq_loss2(float* __restrict__ out,
                                                const float* __restrict__ ws) {
    const float* blk = ws + OFF_BLK;
    __shared__ double sd[256];
    double s = 0.0;
    for (int i = threadIdx.x; i < 16384; i += 256) s += (double)blk[i];
    sd[threadIdx.x] = s;
    __syncthreads();
    for (int off = 128; off; off >>= 1) {
        if (threadIdx.x < off) sd[threadIdx.x] += sd[threadIdx.x + off];
        __syncthreads();
    }
    if (threadIdx.x == 0)
        out[LOSSOFF] = (float)(1.25 * sd[0] / ((double)NTOK * (double)DIM));
}

extern "C" void kernel_launch(void* const* d_in, const int* in_sizes, int n_in,
                              void* d_out, int out_size, void* d_ws, size_t ws_size,
                              hipStream_t stream) {
    (void)in_sizes; (void)n_in; (void)out_size; (void)ws_size;
    const float* x = (const float*)d_in[0];
    const float* cb = (const float*)d_in[1];
    float* out = (float*)d_out;
    float* ws = (float*)d_ws;

    hipLaunchKernelGGL(vq_prep_cb, dim3(4), dim3(256), 0, stream, cb, ws);
    hipLaunchKernelGGL(vq_mfma, dim3(2048), dim3(256), 0, stream, x, out, ws);
    hipLaunchKernelGGL(vq_refine, dim3(1024), dim3(256), 0, stream, x, cb, out, ws);
    hipLaunchKernelGGL(vq_out, dim3(16384), dim3(256), 0, stream, x, cb, out, ws);
    hipLaunchKernelGGL(vq_loss2, dim3(1), dim3(256), 0, stream, out, ws);
}

// Round 8
// 227.871 us; speedup vs baseline: 4.3361x; 1.0937x over previous
//
#include <hip/hip_runtime.h>
#include <math.h>

#define NTOK   262144
#define DIM    64
#define NCODE  1024
#define LOSSOFF (NTOK*DIM)          // 16777216
#define IDXOFF  (NTOK*DIM + 1)

#define MARGIN 8e-5f
#define RCAP   65536

// ws float-offsets
#define OFF_BC     0               // 1024 f
#define OFF_CBHI   1024            // ushort[65536] = 32768 f
#define OFF_CBMID  33792           // 32768 f
#define OFF_RCNT   66560           // 1 (int)
#define OFF_RLIST  66561           // 65536 (int)
#define OFF_BLK    132097          // 16384 f
#define WS_FLOATS  148481

typedef __attribute__((ext_vector_type(8))) short short8;
typedef __attribute__((ext_vector_type(4))) float f32x4;

__device__ __forceinline__ ushort bf16rn(float f) {
    unsigned u = __float_as_uint(f);
    return (ushort)((u + 0x7fffu + ((u >> 16) & 1u)) >> 16);
}
__device__ __forceinline__ float bf16tof(ushort h) {
    return __uint_as_float(((unsigned)h) << 16);
}

__global__ __launch_bounds__(256) void vq_prep_cb(const float* __restrict__ cb,
                                                  float* __restrict__ ws) {
    int c = blockIdx.x * 256 + threadIdx.x;
    if (c == 0) ((int*)ws)[OFF_RCNT] = 0;
    if (c >= NCODE) return;
    ushort* cbh = (ushort*)(ws + OFF_CBHI);
    ushort* cbm = (ushort*)(ws + OFF_CBMID);
    const float4* p = (const float4*)(cb + (size_t)c * DIM);
    float a0 = 0.f, a1 = 0.f, a2 = 0.f, a3 = 0.f;
#pragma unroll
    for (int i = 0; i < 16; i++) {
        float4 v = p[i];
        a0 = fmaf(v.x, v.x, a0); a1 = fmaf(v.y, v.y, a1);
        a2 = fmaf(v.z, v.z, a2); a3 = fmaf(v.w, v.w, a3);
        ushort4 h, m;
        h.x = bf16rn(v.x); m.x = bf16rn(v.x - bf16tof(h.x));
        h.y = bf16rn(v.y); m.y = bf16rn(v.y - bf16tof(h.y));
        h.z = bf16rn(v.z); m.z = bf16rn(v.z - bf16tof(h.z));
        h.w = bf16rn(v.w); m.w = bf16rn(v.w - bf16tof(h.w));
        ((ushort4*)(cbh + (size_t)c * 64))[i] = h;
        ((ushort4*)(cbm + (size_t)c * 64))[i] = m;
    }
    ws[OFF_BC + c] = (a0 + a1) + (a2 + a3);   // exact R2 prep chain
}

// MFMA distance pass. 2-tile-deep pipeline: one barrier pair per 2 tiles,
// prefetch 2 tiles ahead (slack ~= 2-tile compute >= L2 latency, so the
// compiler's pre-barrier vmcnt wait is already satisfied).
__global__ __launch_bounds__(256) void vq_mfma(const float* __restrict__ x,
                                               float* __restrict__ out,
                                               float* __restrict__ ws) {
    __shared__ uint4 smem[2][256];   // 8KB: [tilebuf][chunk(2)][code(16)][granule(8)]
    const float* Bc = ws + OFF_BC;
    const ushort* cbh = (const ushort*)(ws + OFF_CBHI);
    const ushort* cbm = (const ushort*)(ws + OFF_CBMID);

    int tid = threadIdx.x, lane = tid & 63, wv = tid >> 6;
    int col = lane & 15, q = lane >> 4, q4 = q * 4;
    int tokb = blockIdx.x * 128 + wv * 32;

    short8 Xhi[2][2], Xmid[2][2];
    float S[2];
#pragma unroll
    for (int tt = 0; tt < 2; ++tt) {
        int token = tokb + tt * 16 + col;
        const float* xr = x + (size_t)token * 64;
        float ss = 0.f;
#pragma unroll
        for (int s = 0; s < 2; ++s) {
            float4 v0 = *(const float4*)(xr + s * 32 + q * 8);
            float4 v1 = *(const float4*)(xr + s * 32 + q * 8 + 4);
            float vv[8] = {v0.x, v0.y, v0.z, v0.w, v1.x, v1.y, v1.z, v1.w};
            short8 hv, mv;
#pragma unroll
            for (int j = 0; j < 8; ++j) {
                ushort h = bf16rn(vv[j]);
                float r = vv[j] - bf16tof(h);
                hv[j] = (short)h; mv[j] = (short)bf16rn(r);
                ss = fmaf(vv[j], vv[j], ss);
            }
            Xhi[tt][s] = hv; Xmid[tt][s] = mv;
        }
        ss += __shfl_xor(ss, 16, 64);
        ss += __shfl_xor(ss, 32, 64);
        S[tt] = ss;
    }

    // per-slot trackers: slot rr covers codes c0+q*4+rr (static rr indices only)
    float best[2][4], sec[2][4];
    int bbase[2][4];
#pragma unroll
    for (int tt = 0; tt < 2; ++tt)
#pragma unroll
        for (int rr = 0; rr < 4; ++rr) {
            best[tt][rr] = 3.4e38f; sec[tt][rr] = 3.4e38f; bbase[tt][rr] = 0;
        }

    int chunk = tid >> 7, e = tid & 127, scode = e >> 3, g = e & 7;
    const ushort* sb0 = (chunk ? cbm : cbh) + (size_t)scode * 64 + g * 8;
    int woff = chunk * 128 + scode * 8 + (g ^ (scode & 7));
    int ro_h0 = col * 8 + ((0 + q) ^ (col & 7));
    int ro_h1 = col * 8 + ((4 + q) ^ (col & 7));
    int ro_m0 = 128 + col * 8 + ((0 + q) ^ (col & 7));
    int ro_m1 = 128 + col * 8 + ((4 + q) ^ (col & 7));

    uint4 r0 = *(const uint4*)(sb0);          // tile 0 (tile stride = 1024 ushorts)
    uint4 r1 = *(const uint4*)(sb0 + 1024);   // tile 1
    smem[0][woff] = r0; smem[1][woff] = r1;
    __syncthreads();

    for (int t = 0; t < 64; t += 2) {
        if (t + 2 < 64) {   // prefetch 2 tiles ahead; consumed after next barrier
            r0 = *(const uint4*)(sb0 + (size_t)(t + 2) * 1024);
            r1 = *(const uint4*)(sb0 + (size_t)(t + 3) * 1024);
        }
#pragma unroll
        for (int sub = 0; sub < 2; ++sub) {
            int c0 = (t + sub) * 16;
            float4 bq = *(const float4*)(Bc + c0 + q4);
            short8 Ah0 = *(const short8*)&smem[sub][ro_h0];
            short8 Ah1 = *(const short8*)&smem[sub][ro_h1];
            short8 Am0 = *(const short8*)&smem[sub][ro_m0];
            short8 Am1 = *(const short8*)&smem[sub][ro_m1];
            int bv = c0 + q4;
#pragma unroll
            for (int tt = 0; tt < 2; ++tt) {
                f32x4 acc = {0.f, 0.f, 0.f, 0.f};
                acc = __builtin_amdgcn_mfma_f32_16x16x32_bf16(Ah0, Xhi[tt][0], acc, 0, 0, 0);
                acc = __builtin_amdgcn_mfma_f32_16x16x32_bf16(Ah1, Xhi[tt][1], acc, 0, 0, 0);
                acc = __builtin_amdgcn_mfma_f32_16x16x32_bf16(Ah0, Xmid[tt][0], acc, 0, 0, 0);
                acc = __builtin_amdgcn_mfma_f32_16x16x32_bf16(Ah1, Xmid[tt][1], acc, 0, 0, 0);
                acc = __builtin_amdgcn_mfma_f32_16x16x32_bf16(Am0, Xhi[tt][0], acc, 0, 0, 0);
                acc = __builtin_amdgcn_mfma_f32_16x16x32_bf16(Am1, Xhi[tt][1], acc, 0, 0, 0);
                float bqv[4] = {bq.x, bq.y, bq.z, bq.w};
#pragma unroll
                for (int rr = 0; rr < 4; ++rr) {
                    float d = fmaf(-2.f, acc[rr], S[tt] + bqv[rr]);
                    bool lt = d < best[tt][rr];
                    float mx = fmaxf(d, best[tt][rr]);
                    sec[tt][rr] = fminf(sec[tt][rr], mx);
                    best[tt][rr] = fminf(best[tt][rr], d);
                    bbase[tt][rr] = lt ? bv : bbase[tt][rr];
                }
            }
        }
        __syncthreads();
        if (t + 2 < 64) { smem[0][woff] = r0; smem[1][woff] = r1; }
        __syncthreads();
    }

#pragma unroll
    for (int tt = 0; tt < 2; ++tt) {
        // merge 4 slots (ascending rr keeps first-min semantics on ties)
        float b = best[tt][0], s2 = sec[tt][0];
        int bi = bbase[tt][0];
#pragma unroll
        for (int rr = 1; rr < 4; ++rr) {
            float ob = best[tt][rr];
            int oi = bbase[tt][rr] + rr;
            s2 = fminf(fminf(s2, sec[tt][rr]), fmaxf(b, ob));
            bool lt2 = (ob < b) || (ob == b && oi < bi);
            b = lt2 ? ob : b; bi = lt2 ? oi : bi;
        }
#pragma unroll
        for (int off = 16; off <= 32; off <<= 1) {
            float ob = __shfl_xor(b, off, 64);
            float os = __shfl_xor(s2, off, 64);
            int   oi = __shfl_xor(bi, off, 64);
            s2 = fminf(fminf(s2, os), fmaxf(b, ob));
            bool lt = (ob < b) || (ob == b && oi < bi);
            b = lt ? ob : b; bi = lt ? oi : bi;
        }
        if (lane < 16) {
            int token = tokb + tt * 16 + lane;
            out[IDXOFF + token] = (float)bi;
            if (s2 - b < MARGIN) {
                int pos = atomicAdd((int*)ws + OFF_RCNT, 1);
                if (pos < RCAP) ((int*)ws)[OFF_RLIST + pos] = token;
            }
        }
    }
}

// refine: 8 tokens/group; codebook staged coalesced to LDS in 128-code
// tiles (swizzled quads -> conflict-free b128 reads); exact R2 fp32 chains;
// packed (f32bits<<32)|idx u64-min = first-min tiebreak (d>0 always).
__global__ __launch_bounds__(256) void vq_refine(const float* __restrict__ x,
                                                 const float* __restrict__ cb,
                                                 float* __restrict__ out,
                                                 float* __restrict__ ws) {
    __shared__ float ctile[128][64];               // 32KB
    __shared__ float xs[8][64];                    // 2KB
    __shared__ float As[8];
    __shared__ int   tokid[8];
    __shared__ unsigned long long rkeys[8][128];   // 8KB

    int cnt = min(((int*)ws)[OFF_RCNT], RCAP);
    if (cnt <= 0) return;
    int ngroups = (cnt + 7) >> 3;
    int tid = threadIdx.x;
    int code = tid & 127, th = tid >> 7;

    for (int grp = blockIdx.x; grp < ngroups; grp += gridDim.x) {
        if (tid < 8) {
            int i = grp * 8 + tid;
            tokid[tid] = ((int*)ws)[OFF_RLIST + min(i, cnt - 1)];
        }
        __syncthreads();
#pragma unroll
        for (int it = 0; it < 2; ++it) {
            int idx = it * 256 + tid;
            xs[idx >> 6][idx & 63] = x[(size_t)tokid[idx >> 6] * 64 + (idx & 63)];
        }
        __syncthreads();
        if (tid < 8) {
            float a0 = 0.f, a1 = 0.f, a2 = 0.f, a3 = 0.f;
#pragma unroll
            for (int kc = 0; kc < 16; ++kc) {
                float4 xk = *(const float4*)(xs[tid] + kc * 4);
                a0 = fmaf(xk.x, xk.x, a0); a1 = fmaf(xk.y, xk.y, a1);
                a2 = fmaf(xk.z, xk.z, a2); a3 = fmaf(xk.w, xk.w, a3);
            }
            As[tid] = (a0 + a1) + (a2 + a3);
        }

        unsigned long long bk[4] = {~0ull, ~0ull, ~0ull, ~0ull};
        int tb = th * 4;

        for (int pass = 0; pass < 8; ++pass) {
            int cbase = pass * 128;
            __syncthreads();
#pragma unroll
            for (int it = 0; it < 8; ++it) {
                int gi = it * 256 + tid;
                int cc = gi >> 4, qq = gi & 15;
                float4 v = *(const float4*)(cb + (size_t)(cbase + cc) * 64 + qq * 4);
                *(float4*)&ctile[cc][(qq ^ (cc & 15)) * 4] = v;
            }
            __syncthreads();

            float p0 = 0.f, p1 = 0.f, p2 = 0.f, p3 = 0.f;
#pragma unroll
            for (int qq = 0; qq < 16; ++qq) {
                float4 cv = *(const float4*)&ctile[code][(qq ^ (code & 15)) * 4];
                float4 x0 = *(const float4*)(xs[tb + 0] + qq * 4);
                float4 x1 = *(const float4*)(xs[tb + 1] + qq * 4);
                float4 x2 = *(const float4*)(xs[tb + 2] + qq * 4);
                float4 x3 = *(const float4*)(xs[tb + 3] + qq * 4);
                p0 = fmaf(x0.x, cv.x, p0); p0 = fmaf(x0.y, cv.y, p0);
                p0 = fmaf(x0.z, cv.z, p0); p0 = fmaf(x0.w, cv.w, p0);
                p1 = fmaf(x1.x, cv.x, p1); p1 = fmaf(x1.y, cv.y, p1);
                p1 = fmaf(x1.z, cv.z, p1); p1 = fmaf(x1.w, cv.w, p1);
                p2 = fmaf(x2.x, cv.x, p2); p2 = fmaf(x2.y, cv.y, p2);
                p2 = fmaf(x2.z, cv.z, p2); p2 = fmaf(x2.w, cv.w, p2);
                p3 = fmaf(x3.x, cv.x, p3); p3 = fmaf(x3.y, cv.y, p3);
                p3 = fmaf(x3.z, cv.z, p3); p3 = fmaf(x3.w, cv.w, p3);
            }
            float bn = ws[OFF_BC + cbase + code];
            int gcode = cbase + code;
            float pv[4] = {p0, p1, p2, p3};
#pragma unroll
            for (int j = 0; j < 4; ++j) {
                float s = As[tb + j] + bn;
                float d = fmaf(-2.0f, pv[j], s);
                unsigned long long key =
                    (((unsigned long long)__float_as_uint(d)) << 32) | (unsigned)gcode;
                bk[j] = min(bk[j], key);
            }
        }
        __syncthreads();
#pragma unroll
        for (int j = 0; j < 4; ++j) rkeys[tb + j][code] = bk[j];
        __syncthreads();

        int wv2 = tid >> 6, lane = tid & 63;
#pragma unroll
        for (int u = 0; u < 2; ++u) {
            int tt = wv2 * 2 + u;
            unsigned long long k = min(rkeys[tt][lane], rkeys[tt][lane + 64]);
#pragma unroll
            for (int off = 32; off; off >>= 1)
                k = min(k, (unsigned long long)__shfl_xor((long long)k, off, 64));
            if (lane == 0 && grp * 8 + tt < cnt)
                out[IDXOFF + tokid[tt]] = (float)(int)(unsigned)(k & 0xffffffffull);
        }
        __syncthreads();
    }
}

__global__ __launch_bounds__(256) void vq_out(const float* __restrict__ x,
                                              const float* __restrict__ cb,
                                              float* __restrict__ out,
                                              float* __restrict__ ws) {
    int gidx = blockIdx.x * 256 + threadIdx.x;
    int token = gidx >> 4, quad = gidx & 15;
    int ci = (int)out[IDXOFF + token];
    float4 xv = *(const float4*)(x + (size_t)token * 64 + quad * 4);
    float4 qv = *(const float4*)(cb + (size_t)ci * 64 + quad * 4);
    float d0 = qv.x - xv.x, d1 = qv.y - xv.y, d2 = qv.z - xv.z, d3 = qv.w - xv.w;
    float4 o; o.x = xv.x + d0; o.y = xv.y + d1; o.z = xv.z + d2; o.w = xv.w + d3;
    *(float4*)(out + (size_t)token * 64 + quad * 4) = o;
    float se = d0 * d0 + d1 * d1 + d2 * d2 + d3 * d3;
    for (int off = 32; off; off >>= 1) se += __shfl_down(se, off, 64);
    __shared__ float red[4];
    if ((threadIdx.x & 63) == 0) red[threadIdx.x >> 6] = se;
    __syncthreads();
    if (threadIdx.x == 0) ws[OFF_BLK + blockIdx.x] = (red[0] + red[1]) + (red[2] + red[3]);
}

__global__ __launch_bounds__(256) void vq_loss2(float* __restrict__ out,
                                                const float* __restrict__ ws) {
    const float* blk = ws + OFF_BLK;
    __shared__ double sd[256];
    double s = 0.0;
    for (int i = threadIdx.x; i < 16384; i += 256) s += (double)blk[i];
    sd[threadIdx.x] = s;
    __syncthreads();
    for (int off = 128; off; off >>= 1) {
        if (threadIdx.x < off) sd[threadIdx.x] += sd[threadIdx.x + off];
        __syncthreads();
    }
    if (threadIdx.x == 0)
        out[LOSSOFF] = (float)(1.25 * sd[0] / ((double)NTOK * (double)DIM));
}

extern "C" void kernel_launch(void* const* d_in, const int* in_sizes, int n_in,
                              void* d_out, int out_size, void* d_ws, size_t ws_size,
                              hipStream_t stream) {
    (void)in_sizes; (void)n_in; (void)out_size; (void)ws_size;
    const float* x = (const float*)d_in[0];
    const float* cb = (const float*)d_in[1];
    float* out = (float*)d_out;
    float* ws = (float*)d_ws;

    hipLaunchKernelGGL(vq_prep_cb, dim3(4), dim3(256), 0, stream, cb, ws);
    hipLaunchKernelGGL(vq_mfma, dim3(2048), dim3(256), 0, stream, x, out, ws);
    hipLaunchKernelGGL(vq_refine, dim3(1024), dim3(256), 0, stream, x, cb, out, ws);
    hipLaunchKernelGGL(vq_out, dim3(16384), dim3(256), 0, stream, x, cb, out, ws);
    hipLaunchKernelGGL(vq_loss2, dim3(1), dim3(256), 0, stream, out, ws);
}

// Round 11
// 209.498 us; speedup vs baseline: 4.7164x; 1.0877x over previous
//
#include <hip/hip_runtime.h>
#include <math.h>

#define NTOK   262144
#define DIM    64
#define NCODE  1024
#define LOSSOFF (NTOK*DIM)          // 16777216
#define IDXOFF  (NTOK*DIM + 1)

#define MARGIN 1e-4f
#define RCAP   65536

// ws float-offsets
#define OFF_BC     0               // 1024 f
#define OFF_CBHI   1024            // ushort[65536] = 32768 f
#define OFF_CBMID  33792           // 32768 f
#define OFF_RCNT   66560           // 1 int
#define OFF_CORR   66561           // 1 float (loss correction from refine)
#define OFF_RLIST  66562           // 65536 int
#define OFF_BLK    132098          // 2048 f
#define WS_FLOATS  134146

typedef __attribute__((ext_vector_type(8))) short short8;
typedef __attribute__((ext_vector_type(4))) float f32x4;

__device__ __forceinline__ ushort bf16rn(float f) {
    unsigned u = __float_as_uint(f);
    return (ushort)((u + 0x7fffu + ((u >> 16) & 1u)) >> 16);
}
__device__ __forceinline__ float bf16tof(ushort h) {
    return __uint_as_float(((unsigned)h) << 16);
}

__global__ __launch_bounds__(256) void vq_prep_cb(const float* __restrict__ cb,
                                                  float* __restrict__ ws) {
    int c = blockIdx.x * 256 + threadIdx.x;
    if (c == 0) { ((int*)ws)[OFF_RCNT] = 0; ws[OFF_CORR] = 0.f; }
    if (c >= NCODE) return;
    ushort* cbh = (ushort*)(ws + OFF_CBHI);
    ushort* cbm = (ushort*)(ws + OFF_CBMID);
    const float4* p = (const float4*)(cb + (size_t)c * DIM);
    float a0 = 0.f, a1 = 0.f, a2 = 0.f, a3 = 0.f;
#pragma unroll
    for (int i = 0; i < 16; i++) {
        float4 v = p[i];
        a0 = fmaf(v.x, v.x, a0); a1 = fmaf(v.y, v.y, a1);
        a2 = fmaf(v.z, v.z, a2); a3 = fmaf(v.w, v.w, a3);
        ushort4 h, m;
        h.x = bf16rn(v.x); m.x = bf16rn(v.x - bf16tof(h.x));
        h.y = bf16rn(v.y); m.y = bf16rn(v.y - bf16tof(h.y));
        h.z = bf16rn(v.z); m.z = bf16rn(v.z - bf16tof(h.z));
        h.w = bf16rn(v.w); m.w = bf16rn(v.w - bf16tof(h.w));
        ((ushort4*)(cbh + (size_t)c * 64))[i] = h;
        ((ushort4*)(cbm + (size_t)c * 64))[i] = m;
    }
    ws[OFF_BC + c] = (a0 + a1) + (a2 + a3);   // exact R2 prep chain
}

// MFMA distance pass, 4-tile-deep pipeline, fused quantized/loss epilogue.
// Compared quantity is dd = B[c] - 2*x.c (token-invariant shift S dropped:
// argmin and sec-best gaps are shift-invariant; MARGIN absorbs rounding).
__global__ __launch_bounds__(256) void vq_mfma(const float* __restrict__ x,
                                               const float* __restrict__ cbf,
                                               float* __restrict__ out,
                                               float* __restrict__ ws) {
    __shared__ uint4 smem[4][256];   // 16KB: [tilebuf][chunk(2)][code(16)][granule(8)]
    __shared__ int idxs[128];
    __shared__ float red[4];
    const float* Bc = ws + OFF_BC;
    const ushort* cbh = (const ushort*)(ws + OFF_CBHI);
    const ushort* cbm = (const ushort*)(ws + OFF_CBMID);

    int tid = threadIdx.x, lane = tid & 63, wv = tid >> 6;
    int col = lane & 15, q = lane >> 4, q4 = q * 4;
    int tokb = blockIdx.x * 128 + wv * 32;

    short8 Xhi[2][2], Xmid[2][2];
#pragma unroll
    for (int tt = 0; tt < 2; ++tt) {
        int token = tokb + tt * 16 + col;
        const float* xr = x + (size_t)token * 64;
#pragma unroll
        for (int s = 0; s < 2; ++s) {
            float4 v0 = *(const float4*)(xr + s * 32 + q * 8);
            float4 v1 = *(const float4*)(xr + s * 32 + q * 8 + 4);
            float vv[8] = {v0.x, v0.y, v0.z, v0.w, v1.x, v1.y, v1.z, v1.w};
            short8 hv, mv;
#pragma unroll
            for (int j = 0; j < 8; ++j) {
                ushort h = bf16rn(vv[j]);
                float r = vv[j] - bf16tof(h);
                hv[j] = (short)h; mv[j] = (short)bf16rn(r);
            }
            Xhi[tt][s] = hv; Xmid[tt][s] = mv;
        }
    }

    // per-slot trackers: slot rr covers codes c0+q*4+rr
    float best[2][4], sec[2][4];
    int bbase[2][4];
#pragma unroll
    for (int tt = 0; tt < 2; ++tt)
#pragma unroll
        for (int rr = 0; rr < 4; ++rr) {
            best[tt][rr] = 3.4e38f; sec[tt][rr] = 3.4e38f; bbase[tt][rr] = 0;
        }

    int chunk = tid >> 7, e = tid & 127, scode = e >> 3, g = e & 7;
    const ushort* sb0 = (chunk ? cbm : cbh) + (size_t)scode * 64 + g * 8;
    int woff = chunk * 128 + scode * 8 + (g ^ (scode & 7));
    int ro_h0 = col * 8 + ((0 + q) ^ (col & 7));
    int ro_h1 = col * 8 + ((4 + q) ^ (col & 7));
    int ro_m0 = 128 + col * 8 + ((0 + q) ^ (col & 7));
    int ro_m1 = 128 + col * 8 + ((4 + q) ^ (col & 7));

    uint4 r0 = *(const uint4*)(sb0);
    uint4 r1 = *(const uint4*)(sb0 + 1024);
    uint4 r2 = *(const uint4*)(sb0 + 2048);
    uint4 r3 = *(const uint4*)(sb0 + 3072);
    smem[0][woff] = r0; smem[1][woff] = r1;
    smem[2][woff] = r2; smem[3][woff] = r3;
    __syncthreads();

    for (int t = 0; t < 64; t += 4) {
        if (t + 4 < 64) {   // prefetch next round; full-round slack
            r0 = *(const uint4*)(sb0 + (size_t)(t + 4) * 1024);
            r1 = *(const uint4*)(sb0 + (size_t)(t + 5) * 1024);
            r2 = *(const uint4*)(sb0 + (size_t)(t + 6) * 1024);
            r3 = *(const uint4*)(sb0 + (size_t)(t + 7) * 1024);
        }
#pragma unroll
        for (int sub = 0; sub < 4; ++sub) {
            int c0 = (t + sub) * 16;
            float4 bq = *(const float4*)(Bc + c0 + q4);
            short8 Ah0 = *(const short8*)&smem[sub][ro_h0];
            short8 Ah1 = *(const short8*)&smem[sub][ro_h1];
            short8 Am0 = *(const short8*)&smem[sub][ro_m0];
            short8 Am1 = *(const short8*)&smem[sub][ro_m1];
            int bv = c0 + q4;
            float bqv[4] = {bq.x, bq.y, bq.z, bq.w};
#pragma unroll
            for (int tt = 0; tt < 2; ++tt) {
                f32x4 acc = {0.f, 0.f, 0.f, 0.f};
                acc = __builtin_amdgcn_mfma_f32_16x16x32_bf16(Ah0, Xhi[tt][0], acc, 0, 0, 0);
                acc = __builtin_amdgcn_mfma_f32_16x16x32_bf16(Ah1, Xhi[tt][1], acc, 0, 0, 0);
                acc = __builtin_amdgcn_mfma_f32_16x16x32_bf16(Ah0, Xmid[tt][0], acc, 0, 0, 0);
                acc = __builtin_amdgcn_mfma_f32_16x16x32_bf16(Ah1, Xmid[tt][1], acc, 0, 0, 0);
                acc = __builtin_amdgcn_mfma_f32_16x16x32_bf16(Am0, Xhi[tt][0], acc, 0, 0, 0);
                acc = __builtin_amdgcn_mfma_f32_16x16x32_bf16(Am1, Xhi[tt][1], acc, 0, 0, 0);
#pragma unroll
                for (int rr = 0; rr < 4; ++rr) {
                    float d = fmaf(-2.f, acc[rr], bqv[rr]);
                    bool lt = d < best[tt][rr];
                    // med3(d, best, sec) == exact new second-best
                    sec[tt][rr] = __builtin_amdgcn_fmed3f(d, best[tt][rr], sec[tt][rr]);
                    best[tt][rr] = fminf(best[tt][rr], d);
                    bbase[tt][rr] = lt ? bv : bbase[tt][rr];
                }
            }
        }
        __syncthreads();
        if (t + 4 < 64) {
            smem[0][woff] = r0; smem[1][woff] = r1;
            smem[2][woff] = r2; smem[3][woff] = r3;
        }
        __syncthreads();
    }

#pragma unroll
    for (int tt = 0; tt < 2; ++tt) {
        float b = best[tt][0], s2 = sec[tt][0];
        int bi = bbase[tt][0];
#pragma unroll
        for (int rr = 1; rr < 4; ++rr) {
            float ob = best[tt][rr];
            int oi = bbase[tt][rr] + rr;
            s2 = fminf(fminf(s2, sec[tt][rr]), fmaxf(b, ob));
            bool lt2 = (ob < b) || (ob == b && oi < bi);
            b = lt2 ? ob : b; bi = lt2 ? oi : bi;
        }
#pragma unroll
        for (int off = 16; off <= 32; off <<= 1) {
            float ob = __shfl_xor(b, off, 64);
            float os = __shfl_xor(s2, off, 64);
            int   oi = __shfl_xor(bi, off, 64);
            s2 = fminf(fminf(s2, os), fmaxf(b, ob));
            bool lt = (ob < b) || (ob == b && oi < bi);
            b = lt ? ob : b; bi = lt ? oi : bi;
        }
        if (lane < 16) {
            int token = tokb + tt * 16 + lane;
            out[IDXOFF + token] = (float)bi;
            idxs[wv * 32 + tt * 16 + lane] = bi;
            if (s2 - b < MARGIN) {
                int pos = atomicAdd((int*)ws + OFF_RCNT, 1);
                if (pos < RCAP) ((int*)ws)[OFF_RLIST + pos] = token;
            }
        }
    }
    __syncthreads();

    // fused quantized + loss epilogue (refine later corrects flagged rows)
    float se = 0.f;
    int tokb0 = blockIdx.x * 128;
#pragma unroll
    for (int i = 0; i < 8; ++i) {
        int gi = i * 256 + tid;
        int tok = gi >> 4, qd = gi & 15;
        int ci = idxs[tok];
        float4 xvv = *(const float4*)(x + (size_t)(tokb0 + tok) * 64 + qd * 4);
        float4 qv = *(const float4*)(cbf + (size_t)ci * 64 + qd * 4);
        float d0 = qv.x - xvv.x, d1 = qv.y - xvv.y;
        float d2 = qv.z - xvv.z, d3 = qv.w - xvv.w;
        float4 o;
        o.x = xvv.x + d0; o.y = xvv.y + d1; o.z = xvv.z + d2; o.w = xvv.w + d3;
        *(float4*)(out + (size_t)(tokb0 + tok) * 64 + qd * 4) = o;
        se += d0 * d0 + d1 * d1 + d2 * d2 + d3 * d3;
    }
    for (int off = 32; off; off >>= 1) se += __shfl_down(se, off, 64);
    if (lane == 0) red[wv] = se;
    __syncthreads();
    if (tid == 0) ws[OFF_BLK + blockIdx.x] = (red[0] + red[1]) + (red[2] + red[3]);
}

// exact fp32 re-scan for flagged tokens; also fixes quantized rows + loss.
__global__ __launch_bounds__(256) void vq_refine(const float* __restrict__ x,
                                                 const float* __restrict__ cb,
                                                 float* __restrict__ out,
                                                 float* __restrict__ ws) {
    __shared__ float ctile[128][64];               // 32KB
    __shared__ float xs[8][64];
    __shared__ float As[8];
    __shared__ int   tokid[8], oidx[8], nidx[8];
    __shared__ unsigned long long rkeys[8][128];   // 8KB
    __shared__ float dred[4];

    int cnt = min(((int*)ws)[OFF_RCNT], RCAP);
    if (cnt <= 0) return;
    int ngroups = (cnt + 7) >> 3;
    int tid = threadIdx.x;
    int code = tid & 127, th = tid >> 7;

    for (int grp = blockIdx.x; grp < ngroups; grp += gridDim.x) {
        if (tid < 8) {
            int i = grp * 8 + tid;
            int t = ((int*)ws)[OFF_RLIST + min(i, cnt - 1)];
            tokid[tid] = t;
            oidx[tid] = (int)out[IDXOFF + t];
        }
        __syncthreads();
#pragma unroll
        for (int it = 0; it < 2; ++it) {
            int idx = it * 256 + tid;
            xs[idx >> 6][idx & 63] = x[(size_t)tokid[idx >> 6] * 64 + (idx & 63)];
        }
        __syncthreads();
        if (tid < 8) {   // exact R2 A-chain
            float a0 = 0.f, a1 = 0.f, a2 = 0.f, a3 = 0.f;
#pragma unroll
            for (int kc = 0; kc < 16; ++kc) {
                float4 xk = *(const float4*)(xs[tid] + kc * 4);
                a0 = fmaf(xk.x, xk.x, a0); a1 = fmaf(xk.y, xk.y, a1);
                a2 = fmaf(xk.z, xk.z, a2); a3 = fmaf(xk.w, xk.w, a3);
            }
            As[tid] = (a0 + a1) + (a2 + a3);
        }

        unsigned long long bk[4] = {~0ull, ~0ull, ~0ull, ~0ull};
        int tb = th * 4;

        for (int pass = 0; pass < 8; ++pass) {
            int cbase = pass * 128;
            __syncthreads();
#pragma unroll
            for (int it = 0; it < 8; ++it) {
                int gi = it * 256 + tid;
                int cc = gi >> 4, qq = gi & 15;
                float4 v = *(const float4*)(cb + (size_t)(cbase + cc) * 64 + qq * 4);
                *(float4*)&ctile[cc][(qq ^ (cc & 15)) * 4] = v;
            }
            __syncthreads();

            float p0 = 0.f, p1 = 0.f, p2 = 0.f, p3 = 0.f;
#pragma unroll
            for (int qq = 0; qq < 16; ++qq) {
                float4 cv = *(const float4*)&ctile[code][(qq ^ (code & 15)) * 4];
                float4 x0 = *(const float4*)(xs[tb + 0] + qq * 4);
                float4 x1 = *(const float4*)(xs[tb + 1] + qq * 4);
                float4 x2 = *(const float4*)(xs[tb + 2] + qq * 4);
                float4 x3 = *(const float4*)(xs[tb + 3] + qq * 4);
                p0 = fmaf(x0.x, cv.x, p0); p0 = fmaf(x0.y, cv.y, p0);
                p0 = fmaf(x0.z, cv.z, p0); p0 = fmaf(x0.w, cv.w, p0);
                p1 = fmaf(x1.x, cv.x, p1); p1 = fmaf(x1.y, cv.y, p1);
                p1 = fmaf(x1.z, cv.z, p1); p1 = fmaf(x1.w, cv.w, p1);
                p2 = fmaf(x2.x, cv.x, p2); p2 = fmaf(x2.y, cv.y, p2);
                p2 = fmaf(x2.z, cv.z, p2); p2 = fmaf(x2.w, cv.w, p2);
                p3 = fmaf(x3.x, cv.x, p3); p3 = fmaf(x3.y, cv.y, p3);
                p3 = fmaf(x3.z, cv.z, p3); p3 = fmaf(x3.w, cv.w, p3);
            }
            float bn = ws[OFF_BC + cbase + code];
            int gcode = cbase + code;
            float pv[4] = {p0, p1, p2, p3};
#pragma unroll
            for (int j = 0; j < 4; ++j) {
                float s = As[tb + j] + bn;
                float d = fmaf(-2.0f, pv[j], s);   // == fl(s - 2p)
                unsigned long long key =
                    (((unsigned long long)__float_as_uint(d)) << 32) | (unsigned)gcode;
                bk[j] = min(bk[j], key);
            }
        }
        __syncthreads();
#pragma unroll
        for (int j = 0; j < 4; ++j) rkeys[tb + j][code] = bk[j];
        __syncthreads();

        int wv2 = tid >> 6, lane = tid & 63;
#pragma unroll
        for (int u = 0; u < 2; ++u) {
            int tt = wv2 * 2 + u;
            unsigned long long k = min(rkeys[tt][lane], rkeys[tt][lane + 64]);
#pragma unroll
            for (int off = 32; off; off >>= 1)
                k = min(k, (unsigned long long)__shfl_xor((long long)k, off, 64));
            if (lane == 0) {
                int ni = (int)(unsigned)(k & 0xffffffffull);
                nidx[tt] = ni;
                if (grp * 8 + tt < cnt) out[IDXOFF + tokid[tt]] = (float)ni;
            }
        }
        __syncthreads();

        // fix quantized rows + loss delta where index changed
        float delta = 0.f;
        {
            int tok = tid >> 5, e2 = (tid & 31) * 2;
            if (grp * 8 + tok < cnt) {
                int nw = nidx[tok], od = oidx[tok];
                if (nw != od) {
                    float x0 = xs[tok][e2], x1 = xs[tok][e2 + 1];
                    float qn0 = cb[(size_t)nw * 64 + e2], qn1 = cb[(size_t)nw * 64 + e2 + 1];
                    float qo0 = cb[(size_t)od * 64 + e2], qo1 = cb[(size_t)od * 64 + e2 + 1];
                    float dn0 = qn0 - x0, dn1 = qn1 - x1;
                    float do0 = qo0 - x0, do1 = qo1 - x1;
                    out[(size_t)tokid[tok] * 64 + e2]     = x0 + dn0;
                    out[(size_t)tokid[tok] * 64 + e2 + 1] = x1 + dn1;
                    delta = (dn0 * dn0 + dn1 * dn1) - (do0 * do0 + do1 * do1);
                }
            }
        }
        for (int off = 32; off; off >>= 1) delta += __shfl_down(delta, off, 64);
        if ((tid & 63) == 0) dred[tid >> 6] = delta;
        __syncthreads();
        if (tid == 0) {
            float dsum = (dred[0] + dred[1]) + (dred[2] + dred[3]);
            if (dsum != 0.f) atomicAdd(ws + OFF_CORR, dsum);
        }
        __syncthreads();
    }
}

__global__ __launch_bounds__(256) void vq_loss2(float* __restrict__ out,
                                                const float* __restrict__ ws) {
    const float* blk = ws + OFF_BLK;
    __shared__ double sd[256];
    double s = 0.0;
    for (int i = threadIdx.x; i < 2048; i += 256) s += (double)blk[i];
    sd[threadIdx.x] = s;
    __syncthreads();
    for (int off = 128; off; off >>= 1) {
        if (threadIdx.x < off) sd[threadIdx.x] += sd[threadIdx.x + off];
        __syncthreads();
    }
    if (threadIdx.x == 0) {
        double tot = sd[0] + (double)ws[OFF_CORR];
        out[LOSSOFF] = (float)(1.25 * tot / ((double)NTOK * (double)DIM));
    }
}

extern "C" void kernel_launch(void* const* d_in, const int* in_sizes, int n_in,
                              void* d_out, int out_size, void* d_ws, size_t ws_size,
                              hipStream_t stream) {
    (void)in_sizes; (void)n_in; (void)out_size; (void)ws_size;
    const float* x = (const float*)d_in[0];
    const float* cb = (const float*)d_in[1];
    float* out = (float*)d_out;
    float* ws = (float*)d_ws;

    hipLaunchKernelGGL(vq_prep_cb, dim3(4), dim3(256), 0, stream, cb, ws);
    hipLaunchKernelGGL(vq_mfma, dim3(2048), dim3(256), 0, stream, x, cb, out, ws);
    hipLaunchKernelGGL(vq_refine, dim3(1024), dim3(256), 0, stream, x, cb, out, ws);
    hipLaunchKernelGGL(vq_loss2, dim3(1), dim3(256), 0, stream, out, ws);
}